// Round 1
// baseline (846.688 us; speedup 1.0000x reference)
//
#include <hip/hip_runtime.h>

// ManifoldAttentionLayer on MI355X — round 0 (correctness-first bf16 MFMA pipeline)
//
// Pipeline:
//  1) convert x -> bf16 (xb)
//  2) gram[b,m,n] = harmonics·harmonicsT (tiny)
//  3) QKV GEMM (bf16 MFMA 16x16x32, 128x128 block tile):
//       Q'[b,h,l,0:64]  = 0.125*(x@wqT+bq)   (bf16, row stride 128)
//       K'[b,h,l,0:64]  =        x@wkT+bk    (bf16, row stride 128)
//       V [b,h,l,0:64]  =        x@wvT+bv    (bf16, row stride 64)
//  4) bias fold (bilinear resize is separable):
//       Q'[b,h,l,64:128] = 0.1*(gram[b,r0(l),:]*(1-wy) + gram[b,r1(l),:]*wy)
//       K'[b,h,c,64:128] = sparse col weights: (1-wx)@c0, wx@c1
//     => Q'·K'T over 128 dims == q·kT*scale + 0.1*bias exactly (no per-element bias work)
//  5) flash attention (hd_qk=128, hd_v=64), online softmax, P via LDS round-trip
//     -> AO bf16 [4096,1024] (heads merged)
//  6) out = AO@woT + bo (fp32) via same GEMM kernel

using short8  = __attribute__((ext_vector_type(8))) short;
using short4v = __attribute__((ext_vector_type(4))) short;
using float4v = __attribute__((ext_vector_type(4))) float;

#define MFMA16(a, b, c) __builtin_amdgcn_mfma_f32_16x16x32_bf16((a), (b), (c), 0, 0, 0)

static __device__ __forceinline__ short f2bf(float f) {
    union { float f; unsigned u; } v; v.f = f;
    unsigned r = v.u + 0x7fffu + ((v.u >> 16) & 1u);   // round-to-nearest-even
    return (short)(r >> 16);
}

// ---------------- 1) fp32 -> bf16 convert ----------------
__global__ __launch_bounds__(256) void convert_bf16(const float* __restrict__ in,
                                                    short* __restrict__ out, int n4) {
    int idx = blockIdx.x * 256 + threadIdx.x;
    for (int i = idx; i < n4; i += gridDim.x * 256) {
        float4v v = *(const float4v*)(in + (size_t)i * 4);
        short4v o;
        o.x = f2bf(v.x); o.y = f2bf(v.y); o.z = f2bf(v.z); o.w = f2bf(v.w);
        *(short4v*)(out + (size_t)i * 4) = o;
    }
}

// ---------------- 2) gram = harmonics @ harmonicsT ----------------
__global__ __launch_bounds__(256) void gram_kernel(const float* __restrict__ harm,
                                                   float* __restrict__ gram) {
    int b = blockIdx.x;
    __shared__ float hs[64][32];
    int tid = threadIdx.x;
    for (int i = tid; i < 2048; i += 256) hs[i >> 5][i & 31] = harm[(size_t)b * 2048 + i];
    __syncthreads();
    for (int i = tid; i < 4096; i += 256) {
        int m = i >> 6, n = i & 63;
        float s = 0.f;
        for (int k = 0; k < 32; k++) s += hs[m][k] * hs[n][k];
        gram[(size_t)b * 4096 + i] = s;
    }
}

// ---------------- 4) fill augmented dims of Q'/K' ----------------
__global__ __launch_bounds__(256) void fill_aug(const float* __restrict__ gram,
                                                short* __restrict__ Qp,
                                                short* __restrict__ Kp) {
    int b  = blockIdx.y;
    int lc = blockIdx.x;                  // 32 l-chunks of 32
    int tid = threadIdx.x;
    int ll = tid >> 3;                    // 0..31
    int d8 = (tid & 7) * 8;               // 0,8,..,56
    int l  = lc * 32 + ll;

    // torch bilinear align_corners=False grid, out=1024 in=64 (same for rows/cols)
    float src = (l + 0.5f) * 0.0625f - 0.5f;
    if (src < 0.f) src = 0.f;
    int r0 = (int)floorf(src); if (r0 > 63) r0 = 63;
    int r1 = r0 + 1;           if (r1 > 63) r1 = 63;
    float wy = src - (float)r0;

    const float* g0 = gram + ((size_t)b * 64 + r0) * 64 + d8;
    const float* g1 = gram + ((size_t)b * 64 + r1) * 64 + d8;
    short8 qa, ka;
    for (int j = 0; j < 8; j++)
        qa[j] = f2bf(0.1f * (g0[j] * (1.f - wy) + g1[j] * wy));
    for (int j = 0; j < 8; j++) {
        float vv = 0.f;
        if (d8 + j == r0) vv += 1.f - wy;   // col grid identical to row grid
        if (d8 + j == r1) vv += wy;
        ka[j] = f2bf(vv);
    }
    for (int h = 0; h < 16; h++) {
        size_t base = (((size_t)(b * 16 + h) * 1024 + l) << 7) + 64 + d8;
        *(short8*)(Qp + base) = qa;
        *(short8*)(Kp + base) = ka;
    }
}

// ---------------- 3/6) GEMM: C[4096,1024] = A(bf16) @ W(fp32,[N][K])^T + bias ----------------
// mode 0: z-dim selects q/k/v, writes bf16 split-head layouts. mode 1: fp32 out.
__global__ __launch_bounds__(256) void gemm_kernel(
    const short* __restrict__ A,
    const float* __restrict__ W0, const float* __restrict__ W1, const float* __restrict__ W2,
    const float* __restrict__ B0, const float* __restrict__ B1, const float* __restrict__ B2,
    short* __restrict__ Qp, short* __restrict__ Kp, short* __restrict__ Vv,
    float* __restrict__ outF, int mode) {
    const int z = blockIdx.z;
    const float* W  = (z == 0) ? W0 : ((z == 1) ? W1 : W2);
    const float* Bs = (z == 0) ? B0 : ((z == 1) ? B1 : B2);

    __shared__ short As[128][40];   // +8 pad (80B rows, 16B-aligned frag reads)
    __shared__ short Bsh[128][40];

    const int tid  = threadIdx.x;
    const int lane = tid & 63;
    const int wv   = tid >> 6;
    const int wm   = (wv >> 1) * 64;
    const int wn   = (wv & 1) * 64;
    const int l16  = lane & 15;
    const int quad = lane >> 4;
    const int bm   = blockIdx.x * 128;
    const int bn   = blockIdx.y * 128;

    float4v zero4 = {0.f, 0.f, 0.f, 0.f};
    float4v acc[4][4];
    for (int i = 0; i < 4; i++)
        for (int j = 0; j < 4; j++) acc[i][j] = zero4;

    for (int kt = 0; kt < 1024; kt += 32) {
        // A tile: 128x32 bf16, 512 16B-chunks
        for (int c = tid; c < 512; c += 256) {
            int r = c >> 2, c8 = (c & 3) * 8;
            *(short8*)&As[r][c8] = *(const short8*)(A + (size_t)(bm + r) * 1024 + kt + c8);
        }
        // W tile: 128x32 fp32 -> bf16, 1024 float4-chunks
        for (int c = tid; c < 1024; c += 256) {
            int r = c >> 3, c4 = (c & 7) * 4;
            float4v v = *(const float4v*)(W + (size_t)(bn + r) * 1024 + kt + c4);
            short4v o;
            o.x = f2bf(v.x); o.y = f2bf(v.y); o.z = f2bf(v.z); o.w = f2bf(v.w);
            *(short4v*)&Bsh[r][c4] = o;
        }
        __syncthreads();
        short8 af[4], bfr[4];
        for (int mt = 0; mt < 4; mt++) af[mt]  = *(const short8*)&As[wm + mt * 16 + l16][quad * 8];
        for (int nt = 0; nt < 4; nt++) bfr[nt] = *(const short8*)&Bsh[wn + nt * 16 + l16][quad * 8];
        for (int mt = 0; mt < 4; mt++)
            for (int nt = 0; nt < 4; nt++)
                acc[mt][nt] = MFMA16(af[mt], bfr[nt], acc[mt][nt]);
        __syncthreads();
    }

    for (int mt = 0; mt < 4; mt++)
        for (int nt = 0; nt < 4; nt++) {
            int col = bn + wn + nt * 16 + l16;
            float bias = Bs[col];
            for (int r = 0; r < 4; r++) {
                int row = bm + wm + mt * 16 + quad * 4 + r;
                float val = acc[mt][nt][r] + bias;
                if (mode == 1) {
                    outF[(size_t)row * 1024 + col] = val;
                } else {
                    int b = row >> 10, l = row & 1023;
                    int h = col >> 6,  d = col & 63;
                    size_t bhl = (size_t)(b * 16 + h) * 1024 + l;
                    if (z == 0)      Qp[(bhl << 7) + d] = f2bf(val * 0.125f);  // fold hd^-0.5 (exact)
                    else if (z == 1) Kp[(bhl << 7) + d] = f2bf(val);
                    else             Vv[(bhl << 6) + d] = f2bf(val);
                }
            }
        }
}

// ---------------- 5) flash attention: hd_qk=128 (bias folded), hd_v=64 ----------------
__global__ __launch_bounds__(256) void flash_kernel(const short* __restrict__ Qp,
                                                    const short* __restrict__ Kp,
                                                    const short* __restrict__ V,
                                                    short* __restrict__ AO) {
    const int qb = blockIdx.x;   // 16 q-blocks of 64
    const int h  = blockIdx.y;
    const int b  = blockIdx.z;
    const int tid  = threadIdx.x;
    const int lane = tid & 63;
    const int w    = tid >> 6;    // wave 0..3, owns 16 q rows
    const int l16  = lane & 15;
    const int quad = lane >> 4;

    __shared__ short Vt[64][40];       // V^T tile [hd][key32], +8 pad
    __shared__ short Pt[4][16][40];    // per-wave P [q16][key32], +8 pad

    const size_t bh = (size_t)(b * 16 + h);
    const short* Qbase = Qp + ((bh * 1024 + qb * 64 + w * 16 + l16) << 7) + quad * 8;
    short8 qf[4];
    for (int c = 0; c < 4; c++) qf[c] = *(const short8*)(Qbase + c * 32);

    float4v zero4 = {0.f, 0.f, 0.f, 0.f};
    float m_i[4], l_i[4];
    float4v o_acc[4];
    for (int r = 0; r < 4; r++) { m_i[r] = -3.0e38f; l_i[r] = 0.f; }
    for (int nt = 0; nt < 4; nt++) o_acc[nt] = zero4;

    for (int kt = 0; kt < 32; kt++) {
        __syncthreads();   // previous iteration's Vt/Pt reads complete
        {   // cooperative V^T staging: 32 keys x 64 dims
            int kk = tid >> 3, d8 = (tid & 7) * 8;
            const short8 vvv = *(const short8*)(V + ((bh * 1024 + kt * 32 + kk) << 6) + d8);
            for (int j = 0; j < 8; j++) Vt[d8 + j][kk] = vvv[j];
        }
        __syncthreads();

        // S = Q'·K'^T : two 16-key subtiles, 4 MFMAs each (128-dim dot)
        float4v s[2];
        for (int st = 0; st < 2; st++) {
            s[st] = zero4;
            const short* Kb = Kp + ((bh * 1024 + kt * 32 + st * 16 + l16) << 7) + quad * 8;
            for (int c = 0; c < 4; c++) {
                short8 kf = *(const short8*)(Kb + c * 32);
                s[st] = MFMA16(qf[c], kf, s[st]);
            }
        }
        // online softmax; lane's rows are quad*4+r, row-reduce across 16 lanes
        float alpha[4];
        for (int r = 0; r < 4; r++) {
            float mx = fmaxf(s[0][r], s[1][r]);
            for (int off = 8; off > 0; off >>= 1) mx = fmaxf(mx, __shfl_xor(mx, off, 16));
            float mnew = fmaxf(m_i[r], mx);
            alpha[r] = __expf(m_i[r] - mnew);
            m_i[r] = mnew;
            float p0 = __expf(s[0][r] - mnew);
            float p1 = __expf(s[1][r] - mnew);
            s[0][r] = p0; s[1][r] = p1;
            float ps = p0 + p1;
            for (int off = 8; off > 0; off >>= 1) ps += __shfl_xor(ps, off, 16);
            l_i[r] = l_i[r] * alpha[r] + ps;
        }
        // P (C-layout) -> LDS -> A-layout
        for (int st = 0; st < 2; st++)
            for (int r = 0; r < 4; r++)
                Pt[w][quad * 4 + r][st * 16 + l16] = f2bf(s[st][r]);
        __syncthreads();

        for (int nt = 0; nt < 4; nt++)
            for (int r = 0; r < 4; r++) o_acc[nt][r] *= alpha[r];

        short8 pf = *(const short8*)&Pt[w][l16][quad * 8];
        for (int nt = 0; nt < 4; nt++) {
            short8 vf = *(const short8*)&Vt[nt * 16 + l16][quad * 8];
            o_acc[nt] = MFMA16(pf, vf, o_acc[nt]);
        }
    }

    const int row0 = b * 1024 + qb * 64 + w * 16;
    for (int nt = 0; nt < 4; nt++) {
        int col = h * 64 + nt * 16 + l16;
        for (int r = 0; r < 4; r++) {
            float val = o_acc[nt][r] / l_i[r];
            AO[(size_t)(row0 + quad * 4 + r) * 1024 + col] = f2bf(val);
        }
    }
}

extern "C" void kernel_launch(void* const* d_in, const int* in_sizes, int n_in,
                              void* d_out, int out_size, void* d_ws, size_t ws_size,
                              hipStream_t stream) {
    const float* x    = (const float*)d_in[0];
    const float* harm = (const float*)d_in[1];
    const float* wq   = (const float*)d_in[2];
    const float* bq   = (const float*)d_in[3];
    const float* wk   = (const float*)d_in[4];
    const float* bk   = (const float*)d_in[5];
    const float* wv   = (const float*)d_in[6];
    const float* bv   = (const float*)d_in[7];
    const float* wo   = (const float*)d_in[8];
    const float* bo   = (const float*)d_in[9];
    float* outF = (float*)d_out;

    // workspace layout (~58.8 MB)
    short* xb   = (short*)d_ws;               // 4096*1024           bf16  (8 MB)
    short* Qp   = xb + (size_t)4096 * 1024;   // 4*16*1024*128       bf16 (16 MB)
    short* Kp   = Qp + (size_t)4 * 16 * 1024 * 128;                 // (16 MB)
    short* Vv   = Kp + (size_t)4 * 16 * 1024 * 128;  // 4*16*1024*64 (8 MB)
    short* AO   = Vv + (size_t)4 * 16 * 1024 * 64;   // 4096*1024    (8 MB)
    float* gram = (float*)(AO + (size_t)4096 * 1024);// 4*64*64 fp32 (64 KB)

    convert_bf16<<<dim3(1024), dim3(256), 0, stream>>>(x, xb, 1048576);
    gram_kernel<<<dim3(4), dim3(256), 0, stream>>>(harm, gram);
    gemm_kernel<<<dim3(32, 8, 3), dim3(256), 0, stream>>>(
        xb, wq, wk, wv, bq, bk, bv, Qp, Kp, Vv, nullptr, 0);
    fill_aug<<<dim3(32, 4), dim3(256), 0, stream>>>(gram, Qp, Kp);
    flash_kernel<<<dim3(16, 16, 4), dim3(256), 0, stream>>>(Qp, Kp, Vv, AO);
    gemm_kernel<<<dim3(32, 8, 1), dim3(256), 0, stream>>>(
        AO, wo, nullptr, nullptr, bo, nullptr, nullptr,
        nullptr, nullptr, nullptr, outF, 1);
}

// Round 2
// 309.477 us; speedup vs baseline: 2.7359x; 2.7359x over previous
//
#include <hip/hip_runtime.h>

// ManifoldAttentionLayer on MI355X — round 1
// R0 post-mortem: __launch_bounds__(256) w/o min-waves let the allocator
// target 8 waves/EU (<=64 VGPR) and SPILL the 64-reg MFMA accumulator ->
// 1.6 GB scratch writes/dispatch (= 16 MFMA * 16B * 32 iter * 256 thr * 768
// blocks), 450 us/GEMM. Fix: __launch_bounds__(256, 2). Also: weights
// pre-converted to bf16 (staging is now a pure copy), AO aliases xb.

using short8  = __attribute__((ext_vector_type(8))) short;
using short4v = __attribute__((ext_vector_type(4))) short;
using float4v = __attribute__((ext_vector_type(4))) float;

#define MFMA16(a, b, c) __builtin_amdgcn_mfma_f32_16x16x32_bf16((a), (b), (c), 0, 0, 0)

static __device__ __forceinline__ short f2bf(float f) {
    union { float f; unsigned u; } v; v.f = f;
    unsigned r = v.u + 0x7fffu + ((v.u >> 16) & 1u);   // round-to-nearest-even
    return (short)(r >> 16);
}

// ---------------- 1a) x: fp32 -> bf16 ----------------
__global__ __launch_bounds__(256) void convert_bf16(const float* __restrict__ in,
                                                    short* __restrict__ out, int n4) {
    int idx = blockIdx.x * 256 + threadIdx.x;
    for (int i = idx; i < n4; i += gridDim.x * 256) {
        float4v v = *(const float4v*)(in + (size_t)i * 4);
        short4v o;
        o.x = f2bf(v.x); o.y = f2bf(v.y); o.z = f2bf(v.z); o.w = f2bf(v.w);
        *(short4v*)(out + (size_t)i * 4) = o;
    }
}

// ---------------- 1b) 4 weight matrices: fp32 -> bf16 ----------------
__global__ __launch_bounds__(256) void convert_w4(const float* __restrict__ w0,
                                                  const float* __restrict__ w1,
                                                  const float* __restrict__ w2,
                                                  const float* __restrict__ w3,
                                                  short* __restrict__ out) {
    int z = blockIdx.y;
    const float* w = (z == 0) ? w0 : (z == 1) ? w1 : (z == 2) ? w2 : w3;
    short* o = out + (size_t)z * 1048576;
    int idx = blockIdx.x * 256 + threadIdx.x;          // 262144 float4 chunks
    for (int i = idx; i < 262144; i += gridDim.x * 256) {
        float4v v = *(const float4v*)(w + (size_t)i * 4);
        short4v s;
        s.x = f2bf(v.x); s.y = f2bf(v.y); s.z = f2bf(v.z); s.w = f2bf(v.w);
        *(short4v*)(o + (size_t)i * 4) = s;
    }
}

// ---------------- 2) gram = harmonics @ harmonicsT ----------------
__global__ __launch_bounds__(256) void gram_kernel(const float* __restrict__ harm,
                                                   float* __restrict__ gram) {
    int b = blockIdx.x;
    __shared__ float hs[64][32];
    int tid = threadIdx.x;
    for (int i = tid; i < 2048; i += 256) hs[i >> 5][i & 31] = harm[(size_t)b * 2048 + i];
    __syncthreads();
    for (int i = tid; i < 4096; i += 256) {
        int m = i >> 6, n = i & 63;
        float s = 0.f;
        #pragma unroll
        for (int k = 0; k < 32; k++) s += hs[m][k] * hs[n][k];
        gram[(size_t)b * 4096 + i] = s;
    }
}

// ---------------- 4) fill augmented dims of Q'/K' (bias fold) ----------------
__global__ __launch_bounds__(256) void fill_aug(const float* __restrict__ gram,
                                                short* __restrict__ Qp,
                                                short* __restrict__ Kp) {
    int b  = blockIdx.y;
    int lc = blockIdx.x;                  // 32 l-chunks of 32
    int tid = threadIdx.x;
    int ll = tid >> 3;                    // 0..31
    int d8 = (tid & 7) * 8;               // 0,8,..,56
    int l  = lc * 32 + ll;

    // torch bilinear align_corners=False grid, out=1024 in=64
    float src = (l + 0.5f) * 0.0625f - 0.5f;
    if (src < 0.f) src = 0.f;
    int r0 = (int)floorf(src); if (r0 > 63) r0 = 63;
    int r1 = r0 + 1;           if (r1 > 63) r1 = 63;
    float wy = src - (float)r0;

    const float* g0 = gram + ((size_t)b * 64 + r0) * 64 + d8;
    const float* g1 = gram + ((size_t)b * 64 + r1) * 64 + d8;
    short8 qa, ka;
    #pragma unroll
    for (int j = 0; j < 8; j++)
        qa[j] = f2bf(0.1f * (g0[j] * (1.f - wy) + g1[j] * wy));
    #pragma unroll
    for (int j = 0; j < 8; j++) {
        float vv = 0.f;
        if (d8 + j == r0) vv += 1.f - wy;   // col grid identical to row grid
        if (d8 + j == r1) vv += wy;
        ka[j] = f2bf(vv);
    }
    for (int h = 0; h < 16; h++) {
        size_t base = (((size_t)(b * 16 + h) * 1024 + l) << 7) + 64 + d8;
        *(short8*)(Qp + base) = qa;
        *(short8*)(Kp + base) = ka;
    }
}

// ---------------- 3/6) GEMM: C[4096,1024] = A(bf16) @ Wb(bf16,[N][K])^T + bias ----------------
// MODE 0: z selects q/k/v, writes bf16 split-head layouts. MODE 1: fp32 out.
template <int MODE>
__global__ __launch_bounds__(256, 2) void gemm_kernel(
    const short* __restrict__ A,
    const short* __restrict__ Wb,      // [z][1024][1024] bf16
    const float* __restrict__ B0, const float* __restrict__ B1, const float* __restrict__ B2,
    short* __restrict__ Qp, short* __restrict__ Kp, short* __restrict__ Vv,
    float* __restrict__ outF) {
    const int z = blockIdx.z;
    const short* W  = Wb + (size_t)z * 1048576;
    const float* Bs = (z == 0) ? B0 : ((z == 1) ? B1 : B2);

    __shared__ short As[128][40];   // +8 pad (80B rows, 16B-aligned frag reads)
    __shared__ short Bsh[128][40];

    const int tid  = threadIdx.x;
    const int lane = tid & 63;
    const int wv   = tid >> 6;
    const int wm   = (wv >> 1) * 64;
    const int wn   = (wv & 1) * 64;
    const int l16  = lane & 15;
    const int quad = lane >> 4;
    const int bm   = blockIdx.x * 128;
    const int bn   = blockIdx.y * 128;

    float4v zero4 = {0.f, 0.f, 0.f, 0.f};
    float4v acc[4][4];
    #pragma unroll
    for (int i = 0; i < 4; i++)
        #pragma unroll
        for (int j = 0; j < 4; j++) acc[i][j] = zero4;

    for (int kt = 0; kt < 1024; kt += 32) {
        // A + W tiles: each 128x32 bf16 = 512 16B-chunks
        #pragma unroll
        for (int c = tid; c < 512; c += 256) {
            int r = c >> 2, c8 = (c & 3) * 8;
            *(short8*)&As[r][c8]  = *(const short8*)(A + (size_t)(bm + r) * 1024 + kt + c8);
            *(short8*)&Bsh[r][c8] = *(const short8*)(W + (size_t)(bn + r) * 1024 + kt + c8);
        }
        __syncthreads();
        short8 af[4], bfr[4];
        #pragma unroll
        for (int mt = 0; mt < 4; mt++) af[mt]  = *(const short8*)&As[wm + mt * 16 + l16][quad * 8];
        #pragma unroll
        for (int nt = 0; nt < 4; nt++) bfr[nt] = *(const short8*)&Bsh[wn + nt * 16 + l16][quad * 8];
        #pragma unroll
        for (int mt = 0; mt < 4; mt++)
            #pragma unroll
            for (int nt = 0; nt < 4; nt++)
                acc[mt][nt] = MFMA16(af[mt], bfr[nt], acc[mt][nt]);
        __syncthreads();
    }

    #pragma unroll
    for (int mt = 0; mt < 4; mt++)
        #pragma unroll
        for (int nt = 0; nt < 4; nt++) {
            int col = bn + wn + nt * 16 + l16;
            float bias = Bs[col];
            #pragma unroll
            for (int r = 0; r < 4; r++) {
                int row = bm + wm + mt * 16 + quad * 4 + r;
                float val = acc[mt][nt][r] + bias;
                if (MODE == 1) {
                    outF[(size_t)row * 1024 + col] = val;
                } else {
                    int b = row >> 10, l = row & 1023;
                    int h = col >> 6,  d = col & 63;
                    size_t bhl = (size_t)(b * 16 + h) * 1024 + l;
                    if (z == 0)      Qp[(bhl << 7) + d] = f2bf(val * 0.125f);  // fold hd^-0.5
                    else if (z == 1) Kp[(bhl << 7) + d] = f2bf(val);
                    else             Vv[(bhl << 6) + d] = f2bf(val);
                }
            }
        }
}

// ---------------- 5) flash attention: hd_qk=128 (bias folded), hd_v=64 ----------------
__global__ __launch_bounds__(256, 2) void flash_kernel(const short* __restrict__ Qp,
                                                       const short* __restrict__ Kp,
                                                       const short* __restrict__ V,
                                                       short* __restrict__ AO) {
    const int qb = blockIdx.x;   // 16 q-blocks of 64
    const int h  = blockIdx.y;
    const int b  = blockIdx.z;
    const int tid  = threadIdx.x;
    const int lane = tid & 63;
    const int w    = tid >> 6;    // wave 0..3, owns 16 q rows
    const int l16  = lane & 15;
    const int quad = lane >> 4;

    __shared__ short Vt[64][40];       // V^T tile [hd][key32], +8 pad
    __shared__ short Pt[4][16][40];    // per-wave P [q16][key32], +8 pad

    const size_t bh = (size_t)(b * 16 + h);
    const short* Qbase = Qp + ((bh * 1024 + qb * 64 + w * 16 + l16) << 7) + quad * 8;
    short8 qf[4];
    #pragma unroll
    for (int c = 0; c < 4; c++) qf[c] = *(const short8*)(Qbase + c * 32);

    float4v zero4 = {0.f, 0.f, 0.f, 0.f};
    float m_i[4], l_i[4];
    float4v o_acc[4];
    #pragma unroll
    for (int r = 0; r < 4; r++) { m_i[r] = -3.0e38f; l_i[r] = 0.f; }
    #pragma unroll
    for (int nt = 0; nt < 4; nt++) o_acc[nt] = zero4;

    for (int kt = 0; kt < 32; kt++) {
        __syncthreads();   // previous iteration's Vt/Pt reads complete
        {   // cooperative V^T staging: 32 keys x 64 dims
            int kk = tid >> 3, d8 = (tid & 7) * 8;
            const short8 vvv = *(const short8*)(V + ((bh * 1024 + kt * 32 + kk) << 6) + d8);
            #pragma unroll
            for (int j = 0; j < 8; j++) Vt[d8 + j][kk] = vvv[j];
        }
        __syncthreads();

        // S = Q'·K'^T : two 16-key subtiles, 4 MFMAs each (128-dim dot)
        float4v s[2];
        #pragma unroll
        for (int st = 0; st < 2; st++) {
            s[st] = zero4;
            const short* Kb = Kp + ((bh * 1024 + kt * 32 + st * 16 + l16) << 7) + quad * 8;
            #pragma unroll
            for (int c = 0; c < 4; c++) {
                short8 kf = *(const short8*)(Kb + c * 32);
                s[st] = MFMA16(qf[c], kf, s[st]);
            }
        }
        // online softmax; lane's rows are quad*4+r, row-reduce across 16 lanes
        float alpha[4];
        #pragma unroll
        for (int r = 0; r < 4; r++) {
            float mx = fmaxf(s[0][r], s[1][r]);
            #pragma unroll
            for (int off = 8; off > 0; off >>= 1) mx = fmaxf(mx, __shfl_xor(mx, off, 16));
            float mnew = fmaxf(m_i[r], mx);
            alpha[r] = __expf(m_i[r] - mnew);
            m_i[r] = mnew;
            float p0 = __expf(s[0][r] - mnew);
            float p1 = __expf(s[1][r] - mnew);
            s[0][r] = p0; s[1][r] = p1;
            float ps = p0 + p1;
            #pragma unroll
            for (int off = 8; off > 0; off >>= 1) ps += __shfl_xor(ps, off, 16);
            l_i[r] = l_i[r] * alpha[r] + ps;
        }
        // P (C-layout) -> LDS -> A-layout
        #pragma unroll
        for (int st = 0; st < 2; st++)
            #pragma unroll
            for (int r = 0; r < 4; r++)
                Pt[w][quad * 4 + r][st * 16 + l16] = f2bf(s[st][r]);
        __syncthreads();

        #pragma unroll
        for (int nt = 0; nt < 4; nt++)
            #pragma unroll
            for (int r = 0; r < 4; r++) o_acc[nt][r] *= alpha[r];

        short8 pf = *(const short8*)&Pt[w][l16][quad * 8];
        #pragma unroll
        for (int nt = 0; nt < 4; nt++) {
            short8 vf = *(const short8*)&Vt[nt * 16 + l16][quad * 8];
            o_acc[nt] = MFMA16(pf, vf, o_acc[nt]);
        }
    }

    const int row0 = b * 1024 + qb * 64 + w * 16;
    #pragma unroll
    for (int nt = 0; nt < 4; nt++) {
        int col = h * 64 + nt * 16 + l16;
        #pragma unroll
        for (int r = 0; r < 4; r++) {
            float val = o_acc[nt][r] / l_i[r];
            AO[(size_t)(row0 + quad * 4 + r) * 1024 + col] = f2bf(val);
        }
    }
}

extern "C" void kernel_launch(void* const* d_in, const int* in_sizes, int n_in,
                              void* d_out, int out_size, void* d_ws, size_t ws_size,
                              hipStream_t stream) {
    const float* x    = (const float*)d_in[0];
    const float* harm = (const float*)d_in[1];
    const float* wq   = (const float*)d_in[2];
    const float* bq   = (const float*)d_in[3];
    const float* wk   = (const float*)d_in[4];
    const float* bk   = (const float*)d_in[5];
    const float* wv   = (const float*)d_in[6];
    const float* bv   = (const float*)d_in[7];
    const float* wo   = (const float*)d_in[8];
    const float* bo   = (const float*)d_in[9];
    float* outF = (float*)d_out;

    // workspace layout (~56.06 MB, same footprint as R0)
    short* xb   = (short*)d_ws;                        // 4M shorts (8 MB); ALIASED as AO
    short* Qp   = xb + (size_t)4 * 1048576;            // 8M shorts (16 MB)
    short* Kp   = Qp + (size_t)8 * 1048576;            // 8M shorts (16 MB)
    short* Vv   = Kp + (size_t)8 * 1048576;            // 4M shorts (8 MB)
    short* Wqkv = Vv + (size_t)4 * 1048576;            // 3M shorts: wq,wk,wv bf16 (6 MB)
    short* Wob  = Wqkv + (size_t)3 * 1048576;          // 1M shorts: wo bf16 (2 MB)
    float* gram = (float*)(Wob + 1048576);             // 16K floats (64 KB)
    short* AO   = xb;   // alias: xb consumed by QKV GEMM before flash writes AO

    convert_bf16<<<dim3(1024), dim3(256), 0, stream>>>(x, xb, 1048576);
    convert_w4<<<dim3(256, 4), dim3(256), 0, stream>>>(wq, wk, wv, wo, Wqkv);
    gram_kernel<<<dim3(4), dim3(256), 0, stream>>>(harm, gram);
    gemm_kernel<0><<<dim3(32, 8, 3), dim3(256), 0, stream>>>(
        xb, Wqkv, bq, bk, bv, Qp, Kp, Vv, nullptr);
    fill_aug<<<dim3(32, 4), dim3(256), 0, stream>>>(gram, Qp, Kp);
    flash_kernel<<<dim3(16, 16, 4), dim3(256), 0, stream>>>(Qp, Kp, Vv, AO);
    gemm_kernel<1><<<dim3(32, 8, 1), dim3(256), 0, stream>>>(
        AO, Wob, bo, nullptr, nullptr, nullptr, nullptr, nullptr, outF);
}

// Round 3
// 257.565 us; speedup vs baseline: 3.2873x; 1.2015x over previous
//
#include <hip/hip_runtime.h>

// ManifoldAttentionLayer on MI355X — round 2
// R1 post-mortem: flash_kernel latency/barrier-bound (MfmaUtil 6.9%, VALU 22%,
// 1.7e7 LDS conflicts from scalar V^T scatter). Rewrite:
//  - S^T = K·Q^T (swapped MFMA operands): softmax reduce = in-lane + 2 shuffles,
//    and P^T (C-layout) is directly a B-operand for O^T = V^T·P^T -> Pt LDS
//    round-trip + 1 barrier/iter eliminated. Key order of the PV contraction is
//    permuted (sum-invariant); V^T staging stores columns in that slot order.
//  - 64-key iters, 32 q/wave (2 n-tiles): 48 MFMAs per wave per barrier pair.
//  - V^T LDS: [2 buf][64 d][72], col = (g*32+slot)^(d&48): conflict-free writes,
//    optimal b128 reads. Double-buffered, prefetch before compute.
//  - log2(e) folded into Q scales -> native v_exp_f32 (exp2).

using short8  = __attribute__((ext_vector_type(8))) short;
using short4v = __attribute__((ext_vector_type(4))) short;
using float4v = __attribute__((ext_vector_type(4))) float;

#define MFMA16(a, b, c) __builtin_amdgcn_mfma_f32_16x16x32_bf16((a), (b), (c), 0, 0, 0)

#define LOG2E 1.44269504088896f

static __device__ __forceinline__ short f2bf(float f) {
    union { float f; unsigned u; } v; v.f = f;
    unsigned r = v.u + 0x7fffu + ((v.u >> 16) & 1u);   // round-to-nearest-even
    return (short)(r >> 16);
}

// ---------------- 1a) x: fp32 -> bf16 ----------------
__global__ __launch_bounds__(256) void convert_bf16(const float* __restrict__ in,
                                                    short* __restrict__ out, int n4) {
    int idx = blockIdx.x * 256 + threadIdx.x;
    for (int i = idx; i < n4; i += gridDim.x * 256) {
        float4v v = *(const float4v*)(in + (size_t)i * 4);
        short4v o;
        o.x = f2bf(v.x); o.y = f2bf(v.y); o.z = f2bf(v.z); o.w = f2bf(v.w);
        *(short4v*)(out + (size_t)i * 4) = o;
    }
}

// ---------------- 1b) 4 weight matrices: fp32 -> bf16 ----------------
__global__ __launch_bounds__(256) void convert_w4(const float* __restrict__ w0,
                                                  const float* __restrict__ w1,
                                                  const float* __restrict__ w2,
                                                  const float* __restrict__ w3,
                                                  short* __restrict__ out) {
    int z = blockIdx.y;
    const float* w = (z == 0) ? w0 : (z == 1) ? w1 : (z == 2) ? w2 : w3;
    short* o = out + (size_t)z * 1048576;
    int idx = blockIdx.x * 256 + threadIdx.x;
    for (int i = idx; i < 262144; i += gridDim.x * 256) {
        float4v v = *(const float4v*)(w + (size_t)i * 4);
        short4v s;
        s.x = f2bf(v.x); s.y = f2bf(v.y); s.z = f2bf(v.z); s.w = f2bf(v.w);
        *(short4v*)(o + (size_t)i * 4) = s;
    }
}

// ---------------- 2) gram = harmonics @ harmonicsT ----------------
__global__ __launch_bounds__(256) void gram_kernel(const float* __restrict__ harm,
                                                   float* __restrict__ gram) {
    int b = blockIdx.x;
    __shared__ float hs[64][32];
    int tid = threadIdx.x;
    for (int i = tid; i < 2048; i += 256) hs[i >> 5][i & 31] = harm[(size_t)b * 2048 + i];
    __syncthreads();
    for (int i = tid; i < 4096; i += 256) {
        int m = i >> 6, n = i & 63;
        float s = 0.f;
        #pragma unroll
        for (int k = 0; k < 32; k++) s += hs[m][k] * hs[n][k];
        gram[(size_t)b * 4096 + i] = s;
    }
}

// ---------------- 4) fill augmented dims of Q'/K' (bias fold) ----------------
// Q aug carries 0.1*log2e (exp2-domain softmax).
__global__ __launch_bounds__(256) void fill_aug(const float* __restrict__ gram,
                                                short* __restrict__ Qp,
                                                short* __restrict__ Kp) {
    int b  = blockIdx.y;
    int lc = blockIdx.x;
    int tid = threadIdx.x;
    int ll = tid >> 3;
    int d8 = (tid & 7) * 8;
    int l  = lc * 32 + ll;

    float src = (l + 0.5f) * 0.0625f - 0.5f;
    if (src < 0.f) src = 0.f;
    int r0 = (int)floorf(src); if (r0 > 63) r0 = 63;
    int r1 = r0 + 1;           if (r1 > 63) r1 = 63;
    float wy = src - (float)r0;

    const float* g0 = gram + ((size_t)b * 64 + r0) * 64 + d8;
    const float* g1 = gram + ((size_t)b * 64 + r1) * 64 + d8;
    short8 qa, ka;
    #pragma unroll
    for (int j = 0; j < 8; j++)
        qa[j] = f2bf(0.1f * LOG2E * (g0[j] * (1.f - wy) + g1[j] * wy));
    #pragma unroll
    for (int j = 0; j < 8; j++) {
        float vv = 0.f;
        if (d8 + j == r0) vv += 1.f - wy;
        if (d8 + j == r1) vv += wy;
        ka[j] = f2bf(vv);
    }
    for (int h = 0; h < 16; h++) {
        size_t base = (((size_t)(b * 16 + h) * 1024 + l) << 7) + 64 + d8;
        *(short8*)(Qp + base) = qa;
        *(short8*)(Kp + base) = ka;
    }
}

// ---------------- 3/6) GEMM ----------------
template <int MODE>
__global__ __launch_bounds__(256, 2) void gemm_kernel(
    const short* __restrict__ A,
    const short* __restrict__ Wb,
    const float* __restrict__ B0, const float* __restrict__ B1, const float* __restrict__ B2,
    short* __restrict__ Qp, short* __restrict__ Kp, short* __restrict__ Vv,
    float* __restrict__ outF) {
    const int z = blockIdx.z;
    const short* W  = Wb + (size_t)z * 1048576;
    const float* Bs = (z == 0) ? B0 : ((z == 1) ? B1 : B2);

    __shared__ short As[128][40];
    __shared__ short Bsh[128][40];

    const int tid  = threadIdx.x;
    const int lane = tid & 63;
    const int wv   = tid >> 6;
    const int wm   = (wv >> 1) * 64;
    const int wn   = (wv & 1) * 64;
    const int l16  = lane & 15;
    const int quad = lane >> 4;
    const int bm   = blockIdx.x * 128;
    const int bn   = blockIdx.y * 128;

    float4v zero4 = {0.f, 0.f, 0.f, 0.f};
    float4v acc[4][4];
    #pragma unroll
    for (int i = 0; i < 4; i++)
        #pragma unroll
        for (int j = 0; j < 4; j++) acc[i][j] = zero4;

    for (int kt = 0; kt < 1024; kt += 32) {
        #pragma unroll
        for (int c = tid; c < 512; c += 256) {
            int r = c >> 2, c8 = (c & 3) * 8;
            *(short8*)&As[r][c8]  = *(const short8*)(A + (size_t)(bm + r) * 1024 + kt + c8);
            *(short8*)&Bsh[r][c8] = *(const short8*)(W + (size_t)(bn + r) * 1024 + kt + c8);
        }
        __syncthreads();
        short8 af[4], bfr[4];
        #pragma unroll
        for (int mt = 0; mt < 4; mt++) af[mt]  = *(const short8*)&As[wm + mt * 16 + l16][quad * 8];
        #pragma unroll
        for (int nt = 0; nt < 4; nt++) bfr[nt] = *(const short8*)&Bsh[wn + nt * 16 + l16][quad * 8];
        #pragma unroll
        for (int mt = 0; mt < 4; mt++)
            #pragma unroll
            for (int nt = 0; nt < 4; nt++)
                acc[mt][nt] = MFMA16(af[mt], bfr[nt], acc[mt][nt]);
        __syncthreads();
    }

    #pragma unroll
    for (int mt = 0; mt < 4; mt++)
        #pragma unroll
        for (int nt = 0; nt < 4; nt++) {
            int col = bn + wn + nt * 16 + l16;
            float bias = Bs[col];
            #pragma unroll
            for (int r = 0; r < 4; r++) {
                int row = bm + wm + mt * 16 + quad * 4 + r;
                float val = acc[mt][nt][r] + bias;
                if (MODE == 1) {
                    outF[(size_t)row * 1024 + col] = val;
                } else {
                    int b = row >> 10, l = row & 1023;
                    int h = col >> 6,  d = col & 63;
                    size_t bhl = (size_t)(b * 16 + h) * 1024 + l;
                    if (z == 0)      Qp[(bhl << 7) + d] = f2bf(val * (0.125f * LOG2E));
                    else if (z == 1) Kp[(bhl << 7) + d] = f2bf(val);
                    else             Vv[(bhl << 6) + d] = f2bf(val);
                }
            }
        }
}

// ---------------- 5) flash attention (S^T form) ----------------
// grid (8,16,4): 128 q/block, 4 waves x 32 q. 64-key iterations.
__global__ __launch_bounds__(256, 2) void flash_kernel(const short* __restrict__ Qp,
                                                       const short* __restrict__ Kp,
                                                       const short* __restrict__ V,
                                                       short* __restrict__ AO) {
    const int qb = blockIdx.x;
    const int h  = blockIdx.y;
    const int b  = blockIdx.z;
    const int tid  = threadIdx.x;
    const int lane = tid & 63;
    const int w    = tid >> 6;
    const int l16  = lane & 15;
    const int quad = lane >> 4;
    const size_t bh = (size_t)(b * 16 + h);

    // V^T staging: [buf][d=64][72]; value V[key][d] stored at col ((g*32+slot)^ (d&48)),
    // slot = ((key&31)>>2&3)*8 + ((key>>4)&1)*4 + (key&3), g = key>>5.
    __shared__ short Vt[2][64][72];

    // Q fragments (B-operand): lane n=l16 -> q row, k = quad*8+j
    short8 qf[2][4];
    #pragma unroll
    for (int n = 0; n < 2; n++) {
        const short* Qb = Qp + ((bh * 1024 + qb * 128 + w * 32 + n * 16 + l16) << 7) + quad * 8;
        #pragma unroll
        for (int c = 0; c < 4; c++) qf[n][c] = *(const short8*)(Qb + c * 32);
    }

    // staging: thread key = tid&63, d-slice = wave: d = w*16 + r*8 + j
    const int skey = tid & 63;
    const int k32  = skey & 31;
    const int slot = ((k32 >> 2) & 3) * 8 + ((k32 >> 4) & 1) * 4 + (k32 & 3);
    const int scol = ((skey >> 5) * 32 + slot) ^ (w * 16);
    const short* Vbase = V + ((bh * 1024 + skey) << 6) + w * 16;

    float4v zero4 = {0.f, 0.f, 0.f, 0.f};
    float m_i[2] = {-3.0e38f, -3.0e38f};
    float l_i[2] = {0.f, 0.f};
    float4v o_acc[4][2];
    #pragma unroll
    for (int mt = 0; mt < 4; mt++)
        #pragma unroll
        for (int n = 0; n < 2; n++) o_acc[mt][n] = zero4;

    // prologue: stage tile 0 into buf 0
    {
        short8 v0 = *(const short8*)(Vbase);
        short8 v1 = *(const short8*)(Vbase + 8);
        #pragma unroll
        for (int j = 0; j < 8; j++) Vt[0][w * 16 + j][scol] = v0[j];
        #pragma unroll
        for (int j = 0; j < 8; j++) Vt[0][w * 16 + 8 + j][scol] = v1[j];
    }

    for (int kt = 0; kt < 16; kt++) {
        const int buf = kt & 1;
        // prefetch next V tile (global loads; latency hidden by compute below)
        short8 v0, v1;
        if (kt < 15) {
            const short* Vn = Vbase + ((size_t)(kt + 1) * 64 << 6);
            v0 = *(const short8*)(Vn);
            v1 = *(const short8*)(Vn + 8);
        }
        __syncthreads();   // staging writes for buf visible; prior reads of buf done

        // S^T = K·Q^T over 64 keys (4 m-tiles), 128 dims
        float4v s[4][2];
        #pragma unroll
        for (int mt = 0; mt < 4; mt++) {
            const short* Kb = Kp + ((bh * 1024 + kt * 64 + mt * 16 + l16) << 7) + quad * 8;
            short8 kf[4];
            #pragma unroll
            for (int c = 0; c < 4; c++) kf[c] = *(const short8*)(Kb + c * 32);
            #pragma unroll
            for (int n = 0; n < 2; n++) {
                s[mt][n] = zero4;
                #pragma unroll
                for (int c = 0; c < 4; c++)
                    s[mt][n] = MFMA16(kf[c], qf[n][c], s[mt][n]);
            }
        }

        // online softmax in exp2 domain (log2e folded into Q scales)
        float alpha[2];
        #pragma unroll
        for (int n = 0; n < 2; n++) {
            float4v t01, t23;
            #pragma unroll
            for (int r = 0; r < 4; r++) {
                t01[r] = fmaxf(s[0][n][r], s[1][n][r]);
                t23[r] = fmaxf(s[2][n][r], s[3][n][r]);
            }
            float mx = fmaxf(fmaxf(fmaxf(t01[0], t23[0]), fmaxf(t01[1], t23[1])),
                             fmaxf(fmaxf(t01[2], t23[2]), fmaxf(t01[3], t23[3])));
            mx = fmaxf(mx, __shfl_xor(mx, 16, 64));
            mx = fmaxf(mx, __shfl_xor(mx, 32, 64));
            float mnew = fmaxf(m_i[n], mx);
            alpha[n] = __builtin_exp2f(m_i[n] - mnew);
            m_i[n] = mnew;
            float ps = 0.f;
            #pragma unroll
            for (int st = 0; st < 4; st++)
                #pragma unroll
                for (int r = 0; r < 4; r++) {
                    float p = __builtin_exp2f(s[st][n][r] - mnew);
                    s[st][n][r] = p;
                    ps += p;
                }
            ps += __shfl_xor(ps, 16, 64);
            ps += __shfl_xor(ps, 32, 64);
            l_i[n] = l_i[n] * alpha[n] + ps;
            #pragma unroll
            for (int mt = 0; mt < 4; mt++)
                #pragma unroll
                for (int r = 0; r < 4; r++) o_acc[mt][n][r] *= alpha[n];
        }

        // O^T += V^T · P^T  (P^T from C-layout regs: B-frag j = s[2kt + j/4][n][j%4])
        #pragma unroll
        for (int g = 0; g < 2; g++) {
            short8 pf[2];
            #pragma unroll
            for (int n = 0; n < 2; n++) {
                #pragma unroll
                for (int j = 0; j < 4; j++) {
                    pf[n][j]     = f2bf(s[2 * g][n][j]);
                    pf[n][4 + j] = f2bf(s[2 * g + 1][n][j]);
                }
            }
            #pragma unroll
            for (int mt = 0; mt < 4; mt++) {
                short8 vf = *(const short8*)&Vt[buf][mt * 16 + l16][(g * 32 + quad * 8) ^ (mt * 16)];
                #pragma unroll
                for (int n = 0; n < 2; n++)
                    o_acc[mt][n] = MFMA16(vf, pf[n], o_acc[mt][n]);
            }
        }

        // stage prefetched tile into other buffer
        if (kt < 15) {
            __syncthreads();   // ensure buf^1 readers (iter kt-1) are done
            #pragma unroll
            for (int j = 0; j < 8; j++) Vt[buf ^ 1][w * 16 + j][scol] = v0[j];
            #pragma unroll
            for (int j = 0; j < 8; j++) Vt[buf ^ 1][w * 16 + 8 + j][scol] = v1[j];
        }
    }

    // epilogue: O^T[d][q] -> AO[q][h*64+d], short4 stores
    #pragma unroll
    for (int n = 0; n < 2; n++) {
        float inv = 1.0f / l_i[n];
        int row = b * 1024 + qb * 128 + w * 32 + n * 16 + l16;
        #pragma unroll
        for (int mt = 0; mt < 4; mt++) {
            short4v ov;
            #pragma unroll
            for (int r = 0; r < 4; r++) ov[r] = f2bf(o_acc[mt][n][r] * inv);
            *(short4v*)(AO + (size_t)row * 1024 + h * 64 + mt * 16 + quad * 4) = ov;
        }
    }
}

extern "C" void kernel_launch(void* const* d_in, const int* in_sizes, int n_in,
                              void* d_out, int out_size, void* d_ws, size_t ws_size,
                              hipStream_t stream) {
    const float* x    = (const float*)d_in[0];
    const float* harm = (const float*)d_in[1];
    const float* wq   = (const float*)d_in[2];
    const float* bq   = (const float*)d_in[3];
    const float* wk   = (const float*)d_in[4];
    const float* bk   = (const float*)d_in[5];
    const float* wv   = (const float*)d_in[6];
    const float* bv   = (const float*)d_in[7];
    const float* wo   = (const float*)d_in[8];
    const float* bo   = (const float*)d_in[9];
    float* outF = (float*)d_out;

    short* xb   = (short*)d_ws;
    short* Qp   = xb + (size_t)4 * 1048576;
    short* Kp   = Qp + (size_t)8 * 1048576;
    short* Vv   = Kp + (size_t)8 * 1048576;
    short* Wqkv = Vv + (size_t)4 * 1048576;
    short* Wob  = Wqkv + (size_t)3 * 1048576;
    float* gram = (float*)(Wob + 1048576);
    short* AO   = xb;   // alias: xb consumed by QKV GEMM before flash writes AO

    convert_bf16<<<dim3(1024), dim3(256), 0, stream>>>(x, xb, 1048576);
    convert_w4<<<dim3(256, 4), dim3(256), 0, stream>>>(wq, wk, wv, wo, Wqkv);
    gram_kernel<<<dim3(4), dim3(256), 0, stream>>>(harm, gram);
    gemm_kernel<0><<<dim3(32, 8, 3), dim3(256), 0, stream>>>(
        xb, Wqkv, bq, bk, bv, Qp, Kp, Vv, nullptr);
    fill_aug<<<dim3(32, 4), dim3(256), 0, stream>>>(gram, Qp, Kp);
    flash_kernel<<<dim3(8, 16, 4), dim3(256), 0, stream>>>(Qp, Kp, Vv, AO);
    gemm_kernel<1><<<dim3(32, 8, 1), dim3(256), 0, stream>>>(
        AO, Wob, bo, nullptr, nullptr, nullptr, nullptr, nullptr, outF);
}